// Round 16
// baseline (2220.625 us; speedup 1.0000x reference)
//
#include <hip/hip_runtime.h>
#include <hip/hip_bf16.h>

#define BATCH 64
#define SEQ   512
#define ISZ   1024
#define HID   1024
#define OUTSEQ_ELEMS (BATCH * SEQ * HID)   // 33554432
#define NBG   4              // batch groups (16 batches each)
#define NCG   16             // col groups (64 cols each)
#define NBLK  (NBG * NCG)    // 64 blocks

typedef float f32x4 __attribute__((ext_vector_type(4)));
typedef short bf16x8 __attribute__((ext_vector_type(8)));
typedef unsigned u32x4 __attribute__((ext_vector_type(4)));

__device__ __forceinline__ unsigned short f2bf(float f) {
    union { float f; unsigned u; } v; v.f = f;
    unsigned r = v.u + 0x7fffu + ((v.u >> 16) & 1u);   // RNE
    return (unsigned short)(r >> 16);
}

// ---------------------------------------------------------------------------
// Kernel A: xp[m][n] = input[m][:] . Wx[:][n] + b[n]  -> written into d_out.
// (unchanged since R1 — proven, ~180 us)
// ---------------------------------------------------------------------------
__global__ __launch_bounds__(256)
void xproj_gemm(const float* __restrict__ A, const float* __restrict__ W,
                const float* __restrict__ bias, float* __restrict__ C)
{
    __shared__ __align__(16) unsigned short As[128][72];
    __shared__ __align__(16) unsigned short Bs[128][72];
    const int tid  = threadIdx.x;
    const int lane = tid & 63;
    const int wave = tid >> 6;
    const int m0 = blockIdx.y * 128;
    const int n0 = blockIdx.x * 128;
    const int wm = (wave >> 1) * 64;
    const int wn = (wave & 1) * 64;
    const int l15 = lane & 15;
    const int kq8 = (lane >> 4) * 8;

    f32x4 acc[4][4] = {};

    for (int k0 = 0; k0 < ISZ; k0 += 64) {
        #pragma unroll
        for (int i = 0; i < 8; ++i) {
            int idx = tid + i * 256;
            int row = idx >> 4;
            int kq  = idx & 15;
            float4 v = *reinterpret_cast<const float4*>(
                A + (size_t)(m0 + row) * ISZ + k0 + kq * 4);
            unsigned short* dst = &As[row][kq * 4];
            dst[0] = f2bf(v.x); dst[1] = f2bf(v.y);
            dst[2] = f2bf(v.z); dst[3] = f2bf(v.w);
        }
        #pragma unroll
        for (int i = 0; i < 8; ++i) {
            int idx = tid + i * 256;
            int kk = idx >> 5;
            int nq = idx & 31;
            float4 v = *reinterpret_cast<const float4*>(
                W + (size_t)(k0 + kk) * HID + n0 + nq * 4);
            Bs[nq * 4 + 0][kk] = f2bf(v.x);
            Bs[nq * 4 + 1][kk] = f2bf(v.y);
            Bs[nq * 4 + 2][kk] = f2bf(v.z);
            Bs[nq * 4 + 3][kk] = f2bf(v.w);
        }
        __syncthreads();
        #pragma unroll
        for (int kk = 0; kk < 64; kk += 32) {
            const int krd = kk + kq8;
            bf16x8 a[4], b[4];
            #pragma unroll
            for (int mf = 0; mf < 4; ++mf)
                a[mf] = *reinterpret_cast<const bf16x8*>(&As[wm + mf * 16 + l15][krd]);
            #pragma unroll
            for (int nf = 0; nf < 4; ++nf)
                b[nf] = *reinterpret_cast<const bf16x8*>(&Bs[wn + nf * 16 + l15][krd]);
            #pragma unroll
            for (int mf = 0; mf < 4; ++mf)
                #pragma unroll
                for (int nf = 0; nf < 4; ++nf)
                    acc[mf][nf] = __builtin_amdgcn_mfma_f32_16x16x32_bf16(
                        a[mf], b[nf], acc[mf][nf], 0, 0, 0);
        }
        __syncthreads();
    }

    const int r4 = (lane >> 4) * 4;
    #pragma unroll
    for (int nf = 0; nf < 4; ++nf) {
        int col = n0 + wn + nf * 16 + l15;
        float bv = bias[col];
        #pragma unroll
        for (int mf = 0; mf < 4; ++mf) {
            int row = m0 + wm + mf * 16 + r4;
            #pragma unroll
            for (int r = 0; r < 4; ++r)
                C[(size_t)(row + r) * HID + col] = acc[mf][nf][r] + bv;
        }
    }
}

// ---------------------------------------------------------------------------
// Kernel B: flag-free tagged-dataflow RNN — R14 VERBATIM (last-known-good)
// plus exactly ONE change: s_sleep(1) backoff before each selective retry
// re-read (stale check => producers not committed; immediate re-read wastes
// a full IC round trip). Everything else bit-identical to R14.
// ---------------------------------------------------------------------------
__global__ __launch_bounds__(256, 1)
void rnn_flow(const float* __restrict__ W, const float* __restrict__ h0,
              float* __restrict__ out,
              unsigned* __restrict__ hb0, unsigned* __restrict__ hb1)
{
    __shared__ __align__(16) unsigned short lds[2][16 * 1032];   // 66 KB
    const int tid  = threadIdx.x;
    const int lane = tid & 63;
    const int wave = tid >> 6;              // col sub-tile
    const int bg = blockIdx.x >> 4;         // batch-group 0..3
    const int cg = blockIdx.x & 15;         // col-group 0..15
    const int b0 = bg * 16;
    const int c0 = cg * 64;
    const int l15 = lane & 15;
    const int kq8 = (lane >> 4) * 8;
    const int q4  = (lane >> 4) * 4;

    // ---- publish own h_0 slice with tag 0 (write-through) ----
    {
        int row = tid >> 4;
        int c4  = (tid & 15) * 4;
        float4 v = *reinterpret_cast<const float4*>(
            h0 + (size_t)(b0 + row) * HID + c0 + c4);
        u32x4 d;
        d[0] = (unsigned)f2bf(v.x); d[1] = (unsigned)f2bf(v.y);
        d[2] = (unsigned)f2bf(v.z); d[3] = (unsigned)f2bf(v.w);
        unsigned* p = hb0 + (size_t)(b0 + row) * HID + c0 + c4;
        asm volatile("global_store_dwordx4 %0, %1, off sc0 sc1"
                     :: "v"(p), "v"(d) : "memory");
    }

    // ---- Wh cols [c0, c0+64) -> bfr (128 VGPR/lane), 4 LDS passes ----
    bf16x8 bfr[32];
    {
        unsigned short* l0 = &lds[0][0];
        for (int w = 0; w < 4; ++w) {
            #pragma unroll 4
            for (int p = 0; p < 16; ++p) {
                int k  = p * 64 + (tid >> 2);
                int cc = (tid & 3) * 4;
                float4 v = *reinterpret_cast<const float4*>(
                    W + (size_t)(ISZ + k) * HID + c0 + w * 16 + cc);
                l0[(cc + 0) * 1032 + k] = f2bf(v.x);
                l0[(cc + 1) * 1032 + k] = f2bf(v.y);
                l0[(cc + 2) * 1032 + k] = f2bf(v.z);
                l0[(cc + 3) * 1032 + k] = f2bf(v.w);
            }
            __syncthreads();
            if (wave == w) {
                #pragma unroll
                for (int ks = 0; ks < 32; ++ks)
                    bfr[ks] = *reinterpret_cast<const bf16x8*>(
                        &l0[l15 * 1032 + ks * 32 + kq8]);
            }
            __syncthreads();
        }
    }

    const int gcol = c0 + wave * 16 + l15;       // this lane's output column

    float xpv[4];
    #pragma unroll
    for (int j = 0; j < 4; ++j)
        xpv[j] = out[(size_t)(b0 + q4 + j) * (SEQ * HID) + gcol];

    // ---- issue initial stage loads (t=0): row p, col-quad tid*4 ----
    u32x4 q[16];
    #pragma unroll
    for (int p = 0; p < 16; ++p) {
        const unsigned* sp = hb0 + (size_t)(b0 + p) * HID + tid * 4;
        asm volatile("global_load_dwordx4 %0, %1, off sc0 sc1"
                     : "=v"(q[p]) : "v"(sp) : "memory");
    }

    for (int t = 0; t < SEQ; ++t) {
        const unsigned* src = (t & 1) ? hb1 : hb0;
        const unsigned texp = (unsigned)t << 16;

        // ---- drain early-issued loads, then selective retry on stale quads ----
        asm volatile("s_waitcnt vmcnt(0)" ::: "memory");
        unsigned stale = 0;
        #pragma unroll
        for (int p = 0; p < 16; ++p) {
            unsigned bad = (q[p][0] ^ texp) | (q[p][1] ^ texp)
                         | (q[p][2] ^ texp) | (q[p][3] ^ texp);
            if (bad & 0xFFFF0000u) stale |= (1u << p);
        }
        int guard = 0;
        while (stale) {
            __builtin_amdgcn_s_sleep(1);   // R16: backoff — let producers commit
            #pragma unroll
            for (int p = 0; p < 16; ++p) {
                if (stale & (1u << p)) {
                    const unsigned* sp = src + (size_t)(b0 + p) * HID + tid * 4;
                    asm volatile("global_load_dwordx4 %0, %1, off sc0 sc1"
                                 : "=v"(q[p]) : "v"(sp) : "memory");
                }
            }
            asm volatile("s_waitcnt vmcnt(0)" ::: "memory");
            unsigned ns = 0;
            #pragma unroll
            for (int p = 0; p < 16; ++p) {
                if (stale & (1u << p)) {
                    unsigned bad = (q[p][0] ^ texp) | (q[p][1] ^ texp)
                                 | (q[p][2] ^ texp) | (q[p][3] ^ texp);
                    if (bad & 0xFFFF0000u) ns |= (1u << p);
                }
            }
            stale = ns;
            if (++guard > (1 << 14)) break;   // degrade, never hang
        }

        // ---- strip tags -> LDS[t&1] (row p, col-quad tid*4) ----
        unsigned short* lb = &lds[t & 1][0];
        #pragma unroll
        for (int p = 0; p < 16; ++p) {
            unsigned long long d =
                  (unsigned long long)(q[p][0] & 0xFFFFu)
                | ((unsigned long long)(q[p][1] & 0xFFFFu) << 16)
                | ((unsigned long long)(q[p][2] & 0xFFFFu) << 32)
                | ((unsigned long long)(q[p][3] & 0xFFFFu) << 48);
            *reinterpret_cast<unsigned long long*>(&lb[p * 1032 + tid * 4]) = d;
        }
        __syncthreads();   // single barrier per step (LDS double-buffered)

        // ---- prefetch xp[t+1] (plain cached; hides under MFMA phase) ----
        float xpn[4];
        if (t < SEQ - 1) {
            #pragma unroll
            for (int j = 0; j < 4; ++j)
                xpn[j] = out[(size_t)(b0 + q4 + j) * (SEQ * HID)
                             + (size_t)(t + 1) * HID + gcol];
        }

        // ---- fragments + MFMA (accumulation order unchanged) ----
        f32x4 ac0 = {}, ac1 = {}, ac2 = {}, ac3 = {};
        #pragma unroll
        for (int g = 0; g < 4; ++g) {
            bf16x8 Af[8];
            #pragma unroll
            for (int m = 0; m < 8; ++m)
                Af[m] = *reinterpret_cast<const bf16x8*>(
                    &lb[l15 * 1032 + (g * 8 + m) * 32 + kq8]);
            ac0 = __builtin_amdgcn_mfma_f32_16x16x32_bf16(Af[0], bfr[g*8+0], ac0, 0, 0, 0);
            ac1 = __builtin_amdgcn_mfma_f32_16x16x32_bf16(Af[1], bfr[g*8+1], ac1, 0, 0, 0);
            ac2 = __builtin_amdgcn_mfma_f32_16x16x32_bf16(Af[2], bfr[g*8+2], ac2, 0, 0, 0);
            ac3 = __builtin_amdgcn_mfma_f32_16x16x32_bf16(Af[3], bfr[g*8+3], ac3, 0, 0, 0);
            ac0 = __builtin_amdgcn_mfma_f32_16x16x32_bf16(Af[4], bfr[g*8+4], ac0, 0, 0, 0);
            ac1 = __builtin_amdgcn_mfma_f32_16x16x32_bf16(Af[5], bfr[g*8+5], ac1, 0, 0, 0);
            ac2 = __builtin_amdgcn_mfma_f32_16x16x32_bf16(Af[6], bfr[g*8+6], ac2, 0, 0, 0);
            ac3 = __builtin_amdgcn_mfma_f32_16x16x32_bf16(Af[7], bfr[g*8+7], ac3, 0, 0, 0);
        }
        f32x4 acc = (ac0 + ac1) + (ac2 + ac3);

        float hv[4];
        #pragma unroll
        for (int j = 0; j < 4; ++j)
            hv[j] = tanhf(acc[j] + xpv[j]);

        if (t < SEQ - 1) {
            // ---- publish h_t (tag t+1): write-through, pair-packed (R14) ----
            unsigned* dst = (t & 1) ? hb0 : hb1;        // hb[(t+1)&1]
            const unsigned tagv = (unsigned)(t + 1) << 16;
            #pragma unroll
            for (int j = 0; j < 4; ++j) {
                unsigned e  = tagv | (unsigned)f2bf(hv[j]);
                unsigned pe = __shfl(e, lane | 1);      // partner (odd lane) elem
                if ((lane & 1) == 0) {
                    unsigned long long d = (unsigned long long)e
                                         | ((unsigned long long)pe << 32);
                    unsigned* p = dst + (size_t)(b0 + q4 + j) * HID + gcol;
                    asm volatile("global_store_dwordx2 %0, %1, off sc0 sc1"
                                 :: "v"(p), "v"(d) : "memory");
                }
            }
            // ---- early-issue next step's stage loads ----
            #pragma unroll
            for (int p = 0; p < 16; ++p) {
                const unsigned* sp = dst + (size_t)(b0 + p) * HID + tid * 4;
                asm volatile("global_load_dwordx4 %0, %1, off sc0 sc1"
                             : "=v"(q[p]) : "v"(sp) : "memory");
            }
        }

        // ---- self-owned fp32 outputs: PLAIN cached stores ----
        #pragma unroll
        for (int j = 0; j < 4; ++j)
            out[(size_t)(b0 + q4 + j) * (SEQ * HID) + (size_t)t * HID + gcol] = hv[j];
        if (t == SEQ - 1) {
            #pragma unroll
            for (int j = 0; j < 4; ++j)
                out[(size_t)OUTSEQ_ELEMS + (size_t)(b0 + q4 + j) * HID + gcol] = hv[j];
        } else {
            #pragma unroll
            for (int j = 0; j < 4; ++j)
                xpv[j] = xpn[j];
        }
    }
}

extern "C" void kernel_launch(void* const* d_in, const int* in_sizes, int n_in,
                              void* d_out, int out_size, void* d_ws, size_t ws_size,
                              hipStream_t stream)
{
    const float* input = (const float*)d_in[0];
    const float* h0    = (const float*)d_in[1];
    const float* W     = (const float*)d_in[2];
    const float* bias  = (const float*)d_in[3];
    float* out = (float*)d_out;

    unsigned* hb0 = (unsigned*)d_ws;                       // 256 KB
    unsigned* hb1 = hb0 + (size_t)BATCH * HID;             // 256 KB

    // Wipe tag space (0xFFFF never equals a valid tag 0..511). In-graph,
    // so every replay self-cleans; required for the first un-poisoned launch.
    hipMemsetAsync(d_ws, 0xFF, (size_t)2 * BATCH * HID * sizeof(unsigned), stream);

    dim3 gA(HID / 128, (BATCH * SEQ) / 128);   // (8, 256)
    xproj_gemm<<<gA, dim3(256), 0, stream>>>(input, W, bias, out);

    rnn_flow<<<dim3(NBLK), dim3(256), 0, stream>>>(W, h0, out, hb0, hb1);
}